// Round 6
// baseline (310.946 us; speedup 1.0000x reference)
//
#include <hip/hip_runtime.h>

#define STN 9
#define CC 3
#define OWN 96
#define NPIX 9216
#define PLANE 82944           // 288*288
#define PST 28                // padded weight row stride (floats), 112B rows -> b128-aligned
#define LDSF (9*3*16*PST)     // 12096 floats = 48384 B

typedef float f4v __attribute__((ext_vector_type(4)));

__global__ __launch_bounds__(192)
void lfk6(const float* __restrict__ lf, const float* __restrict__ wts,
          const float* __restrict__ bias, float* __restrict__ out)
{
    __shared__ float ldsW[LDSF];
    const int tid = threadIdx.x;
    // XCD-bijective swizzle (1728 % 8 == 0)
    const int bid = blockIdx.x;
    const int swz = (bid & 7) * 216 + (bid >> 3);
    const int tile = swz / 3;
    const int og   = swz - tile * 3;
    const int oh   = tile / 6;
    const int tc   = tile - oh * 6;
    const int pix  = tid & 15;
    const int bcq  = tid >> 4;           // 0..11
    const int b    = bcq / 3;
    const int c    = bcq - b * 3;
    const int g    = tile * 16 + pix;
    const int ow   = tc * 16 + pix;
    const int y0   = oh * 3 - 2;         // pt = pl = 2, no bottom/right pad
    const int x0   = ow * 3 - 2;
    const int xcl  = (x0 < 0) ? 0 : x0;
    const bool xneg = (x0 < 0);          // only possible when tc==0 (pix==0)
    const bool tc0  = (tc == 0);         // wave-uniform

    // ---- stage ALL weights for (tile, og): 27 chunks (3 ol x 9 i) x 100 f4 ----
    const f4v* __restrict__ w4 = (const f4v*)wts;
    #pragma unroll
    for (int j = 0; j < 15; ++j) {
        const int idx = tid + 192 * j;
        if (idx < 2700) {
            const int chunk = idx / 100;          // = ol*9 + il
            const int rem   = idx - chunk * 100;
            const f4v v = w4[(og * 27 + chunk) * 57600 + tile * 100 + rem];
            const int ol   = chunk / 9;
            const int il   = chunk - ol * 9;
            const int rowb = il * 48 + ol * 16;
            const int f0   = rem * 4;
            #pragma unroll
            for (int q = 0; q < 4; ++q) {
                const int f  = f0 + q;
                const int pd = f / 25;
                const int k  = f - pd * 25;
                ldsW[(rowb + pd) * PST + k] = v[q];
            }
        }
    }
    __syncthreads();

    // ---- barrier-free compute: 9 i's, patches direct from global ----
    float acc[3] = {0.f, 0.f, 0.f};
    const int pbase0 = (b * 27 + c) * PLANE + xcl;
    const int wpix   = pix * PST;

    #pragma unroll
    for (int i = 0; i < STN; ++i) {
        float p[5][5];
        const float* lfp = lf + pbase0 + i * (3 * PLANE);
        #pragma unroll
        for (int kh = 0; kh < 5; ++kh) {
            const int y = y0 + kh;                // wave-uniform
            if (y >= 0) {
                const float* rp = lfp + y * 288;
                f4v A;
                __builtin_memcpy(&A, rp, 16);     // 4B-aligned dwordx4
                const float Bv = rp[4];
                if (tc0) {                         // wave-uniform branch
                    p[kh][0] = xneg ? 0.f : A.x;
                    p[kh][1] = xneg ? 0.f : A.y;
                    p[kh][2] = xneg ? A.x : A.z;
                    p[kh][3] = xneg ? A.y : A.w;
                    p[kh][4] = xneg ? A.z : Bv;
                } else {
                    p[kh][0] = A.x; p[kh][1] = A.y; p[kh][2] = A.z;
                    p[kh][3] = A.w; p[kh][4] = Bv;
                }
            } else {
                p[kh][0] = p[kh][1] = p[kh][2] = p[kh][3] = p[kh][4] = 0.f;
            }
        }
        #pragma unroll
        for (int oc = 0; oc < 3; ++oc) {
            const float* wrow = &ldsW[(i * 48 + oc * 16) * PST + wpix];
            #pragma unroll
            for (int kh = 0; kh < 5; ++kh)
                #pragma unroll
                for (int kw = 0; kw < 5; ++kw)
                    acc[oc] = fmaf(wrow[kh * 5 + kw], p[kh][kw], acc[oc]);
        }
    }

    // ---- epilogue ----
    #pragma unroll
    for (int oc = 0; oc < 3; ++oc) {
        const int o = og * 3 + oc;
        float v = acc[oc] + bias[o * NPIX + g];
        v = fminf(fmaxf(v, 0.f), 1.f);
        out[((b * STN + o) * CC + c) * NPIX + g] = v;
    }
}

extern "C" void kernel_launch(void* const* d_in, const int* in_sizes, int n_in,
                              void* d_out, int out_size, void* d_ws, size_t ws_size,
                              hipStream_t stream) {
    const float* lf   = (const float*)d_in[0];
    const float* wts  = (const float*)d_in[1];
    const float* bias = (const float*)d_in[2];
    float* out = (float*)d_out;
    (void)d_ws; (void)ws_size; (void)in_sizes; (void)n_in; (void)out_size;

    dim3 grid(576 * 3);     // 1728 blocks
    dim3 block(192);
    lfk6<<<grid, block, 0, stream>>>(lf, wts, bias, out);
}

// Round 7
// 69.136 us; speedup vs baseline: 4.4976x; 4.4976x over previous
//
#include <hip/hip_runtime.h>

#define STN 9
#define CC 3
#define OWN 96
#define NPIX 9216
#define PLANE 82944           // 288*288
#define PST 28                // padded weight row stride (floats), 112B rows -> b128-aligned
#define LDSF (9*3*16*PST)     // 12096 floats = 48384 B

typedef float f4v __attribute__((ext_vector_type(4)));

__global__ __launch_bounds__(192)
void lfk7(const float* __restrict__ lf, const float* __restrict__ wts,
          const float* __restrict__ bias, float* __restrict__ out)
{
    __shared__ float ldsW[LDSF];
    const int tid = threadIdx.x;
    // XCD-bijective swizzle (1728 % 8 == 0)
    const int bid = blockIdx.x;
    const int swz = (bid & 7) * 216 + (bid >> 3);
    const int tile = swz / 3;
    const int og   = swz - tile * 3;
    const int oh   = tile / 6;
    const int tc   = tile - oh * 6;
    const int pix  = tid & 15;
    const int bcq  = tid >> 4;           // 0..11
    const int b    = bcq / 3;
    const int c    = bcq - b * 3;
    const int g    = tile * 16 + pix;
    const int ow   = tc * 16 + pix;
    const int y0   = oh * 3 - 2;         // pt = pl = 2, no bottom/right pad
    const int x0   = ow * 3 - 2;
    const int xcl  = (x0 < 0) ? 0 : x0;
    const bool xneg = (x0 < 0);          // only pix==0 in tc==0 blocks
    const bool tc0  = (tc == 0);         // wave-uniform

    // ---- stage ALL weights for (tile, og): 27 chunks (3 ol x 9 il) x 100 f4 ----
    const f4v* __restrict__ w4 = (const f4v*)wts;
    #pragma unroll
    for (int j = 0; j < 15; ++j) {
        const int idx = tid + 192 * j;
        if (idx < 2700) {
            const int chunk = idx / 100;          // = ol*9 + il
            const int rem   = idx - chunk * 100;
            const f4v v = w4[(og * 27 + chunk) * 57600 + tile * 100 + rem];
            const int ol   = chunk / 9;
            const int il   = chunk - ol * 9;
            const int rowb = il * 48 + ol * 16;
            const int f0   = rem * 4;
            #pragma unroll
            for (int q = 0; q < 4; ++q) {
                const int f  = f0 + q;
                const int pd = f / 25;
                const int k  = f - pd * 25;
                ldsW[(rowb + pd) * PST + k] = v[q];
            }
        }
    }
    __syncthreads();

    float acc[3] = {0.f, 0.f, 0.f};
    const int pbase0 = (b * 27 + c) * PLANE + xcl;
    const int wpix   = pix * PST;

    auto loadP = [&](float (&p)[5][5], int i) {
        const float* lfp = lf + pbase0 + i * (3 * PLANE);
        #pragma unroll
        for (int kh = 0; kh < 5; ++kh) {
            const int y = y0 + kh;                // wave-uniform
            if (y >= 0) {
                const float* rp = lfp + y * 288;
                f4v A;
                __builtin_memcpy(&A, rp, 16);     // 4B-aligned dwordx4
                const float Bv = rp[4];
                if (tc0) {                         // wave-uniform branch
                    p[kh][0] = xneg ? 0.f : A.x;
                    p[kh][1] = xneg ? 0.f : A.y;
                    p[kh][2] = xneg ? A.x : A.z;
                    p[kh][3] = xneg ? A.y : A.w;
                    p[kh][4] = xneg ? A.z : Bv;
                } else {
                    p[kh][0] = A.x; p[kh][1] = A.y; p[kh][2] = A.z;
                    p[kh][3] = A.w; p[kh][4] = Bv;
                }
            } else {
                p[kh][0] = p[kh][1] = p[kh][2] = p[kh][3] = p[kh][4] = 0.f;
            }
        }
    };
    auto computeI = [&](const float (&p)[5][5], int i) {
        #pragma unroll
        for (int oc = 0; oc < 3; ++oc) {
            const float* wrow = &ldsW[(i * 48 + oc * 16) * PST + wpix];
            #pragma unroll
            for (int kh = 0; kh < 5; ++kh)
                #pragma unroll
                for (int kw = 0; kw < 5; ++kw)
                    acc[oc] = fmaf(wrow[kh * 5 + kw], p[kh][kw], acc[oc]);
        }
    };

    // ---- manual 2-deep pipeline; unroll 1 prevents the R6 hoist-all spill ----
    float pA[5][5], pB[5][5];
    loadP(pA, 0);
    #pragma unroll 1
    for (int i = 0; i < 8; i += 2) {
        loadP(pB, i + 1);      // issue early: latency hides under compute(pA)
        computeI(pA, i);
        loadP(pA, i + 2);      // i+2 <= 8 always
        computeI(pB, i + 1);
    }
    computeI(pA, 8);

    // ---- epilogue ----
    #pragma unroll
    for (int oc = 0; oc < 3; ++oc) {
        const int o = og * 3 + oc;
        float v = acc[oc] + bias[o * NPIX + g];
        v = fminf(fmaxf(v, 0.f), 1.f);
        out[((b * STN + o) * CC + c) * NPIX + g] = v;
    }
}

extern "C" void kernel_launch(void* const* d_in, const int* in_sizes, int n_in,
                              void* d_out, int out_size, void* d_ws, size_t ws_size,
                              hipStream_t stream) {
    const float* lf   = (const float*)d_in[0];
    const float* wts  = (const float*)d_in[1];
    const float* bias = (const float*)d_in[2];
    float* out = (float*)d_out;
    (void)d_ws; (void)ws_size; (void)in_sizes; (void)n_in; (void)out_size;

    dim3 grid(576 * 3);     // 1728 blocks
    dim3 block(192);
    lfk7<<<grid, block, 0, stream>>>(lf, wts, bias, out);
}

// Round 8
// 57.323 us; speedup vs baseline: 5.4245x; 1.2061x over previous
//
#include <hip/hip_runtime.h>

#define STN 9
#define CC 3
#define NPIX 9216
#define PLANE 82944           // 288*288
#define W4CH 57600            // float4 per (o,i) weight plane
#define ISTEP (3*PLANE)       // lf float step per i

typedef float f4v __attribute__((ext_vector_type(4)));

__global__ __launch_bounds__(192)
void lfk8(const float* __restrict__ lf, const float* __restrict__ wts,
          const float* __restrict__ bias, float* __restrict__ out)
{
    __shared__ f4v ldsW[2][300];          // 9.6 KB total, packed identity layout
    const int tid = threadIdx.x;
    const int bid = blockIdx.x;
    const int swz = (bid & 7) * 216 + (bid >> 3);   // bijective, og-triples same XCD
    const int tile = swz / 3;
    const int og   = swz - tile * 3;
    const int oh   = tile / 6;
    const int tc   = tile - oh * 6;
    const int px   = tid & 15;
    const int bc   = tid >> 4;            // 0..11
    const int b    = bc / 3;
    const int c    = bc - b * 3;
    const int g    = tile * 16 + px;
    const int ow   = tc * 16 + px;
    const int y0   = oh * 3 - 2;          // pt = pl = 2, no bottom/right pad
    const int x0   = ow * 3 - 2;
    const int xcl  = (x0 < 0) ? 0 : x0;
    const bool xneg = (x0 < 0);           // only px==0 in tc==0 blocks
    const bool tc0  = (tc == 0);          // wave-uniform
    const bool p15  = (px == 15);

    // ---- weight staging descriptors: thread j handles f4 idx j, j+192 ----
    const f4v* __restrict__ w4 = (const f4v*)wts;
    const int j2   = tid + 192;
    const bool has2 = (j2 < 300);
    const int ol1 = tid / 100, rem1 = tid - ol1 * 100;
    const int ol2 = j2  / 100, rem2 = j2  - ol2 * 100;
    const int wg1 = (og * 3 + ol1) * 9 * W4CH + tile * 100 + rem1;   // + i*W4CH
    const int wg2 = (og * 3 + ol2) * 9 * W4CH + tile * 100 + rem2;

    const float* lfb = lf + (b * 27 + c) * PLANE + xcl;

    f4v wA0, wA1, wB0, wB1;
    f4v pA[5], pB[5];
    float eA[5], eB[5];
    float acc[3] = {0.f, 0.f, 0.f};

    auto loadW = [&](f4v& r0, f4v& r1, int i) {
        r0 = w4[wg1 + i * W4CH];
        if (has2) r1 = w4[wg2 + i * W4CH];
    };
    auto writeW = [&](const f4v& r0, const f4v& r1, int buf) {
        ldsW[buf][tid] = r0;
        if (has2) ldsW[buf][j2] = r1;
    };
    auto loadP = [&](f4v (&p)[5], float (&e)[5], int i) {
        const float* lfp = lfb + i * ISTEP;
        #pragma unroll
        for (int kh = 0; kh < 5; ++kh) {
            const int y = y0 + kh;            // wave-uniform
            e[kh] = 0.f;
            if (y >= 0) {
                const float* rp = lfp + y * 288;
                __builtin_memcpy(&p[kh], rp, 16);      // unaligned-ok dwordx4
                if (p15) e[kh] = rp[4];                // 4/64-lane masked dword
            } else {
                p[kh] = (f4v)0.f;
            }
        }
    };
    auto computeI = [&](const f4v (&p)[5], const float (&e)[5], int buf) {
        const float* wb = (const float*)&ldsW[buf][0];
        #pragma unroll
        for (int kh = 0; kh < 5; ++kh) {
            float q0, q1, q2, q3, q4;
            const float sh = __shfl_down(p[kh].y, 1);  // neighbor px overlap
            q4 = p15 ? e[kh] : sh;
            if (tc0) {                                  // wave-uniform branch
                q0 = xneg ? 0.f : p[kh].x;
                q1 = xneg ? 0.f : p[kh].y;
                q2 = xneg ? p[kh].x : p[kh].z;
                q3 = xneg ? p[kh].y : p[kh].w;          // q4 correct for xneg too
            } else {
                q0 = p[kh].x; q1 = p[kh].y; q2 = p[kh].z; q3 = p[kh].w;
            }
            #pragma unroll
            for (int oc = 0; oc < 3; ++oc) {
                const float* wrow = wb + oc * 400 + px * 25 + kh * 5;  // stride-25: conflict-free
                acc[oc] = fmaf(wrow[0], q0, acc[oc]);
                acc[oc] = fmaf(wrow[1], q1, acc[oc]);
                acc[oc] = fmaf(wrow[2], q2, acc[oc]);
                acc[oc] = fmaf(wrow[3], q3, acc[oc]);
                acc[oc] = fmaf(wrow[4], q4, acc[oc]);
            }
        }
    };

    // ---- prologue ----
    loadP(pA, eA, 0);
    loadW(wA0, wA1, 0);

    // ---- 2-deep pipeline, 1 barrier/iter; unroll 1 prevents hoist-spill ----
    #pragma unroll 1
    for (int i = 0; i < 8; i += 2) {
        loadP(pB, eB, i + 1);  loadW(wB0, wB1, i + 1);
        writeW(wA0, wA1, 0);
        __syncthreads();
        computeI(pA, eA, 0);

        loadP(pA, eA, i + 2);  loadW(wA0, wA1, i + 2);   // i+2 <= 8 always
        writeW(wB0, wB1, 1);
        __syncthreads();
        computeI(pB, eB, 1);
    }
    // tail i = 8
    writeW(wA0, wA1, 0);
    __syncthreads();
    computeI(pA, eA, 0);

    // ---- epilogue ----
    #pragma unroll
    for (int oc = 0; oc < 3; ++oc) {
        const int o = og * 3 + oc;
        float v = acc[oc] + bias[o * NPIX + g];
        v = fminf(fmaxf(v, 0.f), 1.f);
        out[((b * STN + o) * CC + c) * NPIX + g] = v;
    }
}

extern "C" void kernel_launch(void* const* d_in, const int* in_sizes, int n_in,
                              void* d_out, int out_size, void* d_ws, size_t ws_size,
                              hipStream_t stream) {
    const float* lf   = (const float*)d_in[0];
    const float* wts  = (const float*)d_in[1];
    const float* bias = (const float*)d_in[2];
    float* out = (float*)d_out;
    (void)d_ws; (void)ws_size; (void)in_sizes; (void)n_in; (void)out_size;

    dim3 grid(576 * 3);     // 1728 blocks x 3 waves
    dim3 block(192);
    lfk8<<<grid, block, 0, stream>>>(lf, wts, bias, out);
}